// Round 9
// baseline (84.105 us; speedup 1.0000x reference)
//
#include <hip/hip_runtime.h>

typedef __attribute__((ext_vector_type(8))) short short8;
typedef __attribute__((ext_vector_type(4))) short short4v;
typedef __attribute__((ext_vector_type(4))) float f32x4;
typedef unsigned int uint32;
typedef unsigned short ushort_t;

// LDS layout (bytes). All bf16 tiles, 128B row stride, XOR-swizzled. 32 KB.
// GHT region is time-shared: Qw staging -> (barrier) -> G -> HT.
#define LDS_FB   0u        // F   [128][64]
#define LDS_GHT  16384u    // Qw staging, then G, then HT [64][64]
#define LDS_KB   24576u    // Kw  [64][64] row-major

__device__ __forceinline__ uint32 swzb(uint32 base, uint32 row, uint32 colByte) {
    return (base + row * 128u + colByte) ^ ((row & 7u) << 4);
}
__device__ __forceinline__ uint32 pk2(float lo, float hi) {   // v_cvt_pk_bf16_f32 (RNE)
    uint32 r;
    asm("v_cvt_pk_bf16_f32 %0, %1, %2" : "=v"(r) : "v"(lo), "v"(hi));
    return r;
}
__device__ __forceinline__ ushort_t bfbits(float x) {         // RNE f32 -> bf16 bits
    uint32 u = __float_as_uint(x);
    return (ushort_t)((u + 0x7FFFu + ((u >> 16) & 1u)) >> 16);
}
__device__ __forceinline__ float bf2f(ushort_t b) {
    return __uint_as_float(((uint32)b) << 16);
}
__device__ __forceinline__ short4v tr16(uint32 addr) {        // ds_read_b64_tr_b16
    short4v d;
    asm volatile("ds_read_b64_tr_b16 %0, %1" : "=v"(d) : "v"(addr));
    return d;
}
#define CAT8(lo, hi) __builtin_shufflevector(lo, hi, 0, 1, 2, 3, 4, 5, 6, 7)
#define MFMA(a, b, c) __builtin_amdgcn_mfma_f32_16x16x32_bf16((a), (b), (c), 0, 0, 0)
#define FENCE_LGKM0() do {                                                     \
    asm volatile("s_waitcnt lgkmcnt(0)" ::: "memory");                         \
    __builtin_amdgcn_sched_barrier(0);                                         \
} while (0)

__global__ __launch_bounds__(256, 5)
void sam3e_kernel(const float* __restrict__ F,
                  const float* __restrict__ Kw,
                  const float* __restrict__ Qw,
                  float* __restrict__ out) {
    __shared__ __align__(128) unsigned char smem[32768];
    const uint32 ldsb = (uint32)(size_t)(void*)smem;
    const int t    = threadIdx.x;
    const int lane = t & 63;
    const int wave = t >> 6;
    const int b    = blockIdx.x;
    const uint32 r16 = (uint32)(lane & 15);
    const uint32 kq  = (uint32)(lane >> 4);
    const uint32 trc = 8u * (r16 & 3u);
    const uint32 trr = r16 >> 2;

    // ---- stage F (batch b) -> bf16 LDS, row-major (HW cvt_pk)
    const float* Fg = F + (size_t)b * 8192;
    {
        int n0 = t >> 4;
        int c4 = (t & 15) * 4;
        #pragma unroll
        for (int i = 0; i < 8; ++i) {
            int n = n0 + 16 * i;
            float4 v = *(const float4*)(Fg + n * 64 + c4);
            uint2 pk; pk.x = pk2(v.x, v.y); pk.y = pk2(v.z, v.w);
            *(uint2*)(smem + swzb(LDS_FB, (uint32)n, (uint32)(2 * c4))) = pk;
        }
    }
    // ---- stage Kw -> KB, Qw -> GHT (time-shared; coalesced float4 loads)
    #pragma unroll
    for (int i = 0; i < 4; ++i) {
        int idx4 = t + 256 * i;
        uint32 r = (uint32)(idx4 >> 4);
        uint32 cB = (uint32)((idx4 & 15) * 8);
        float4 vk = *(const float4*)(Kw + 4 * idx4);
        float4 vq = *(const float4*)(Qw + 4 * idx4);
        uint2 pk; pk.x = pk2(vk.x, vk.y); pk.y = pk2(vk.z, vk.w);
        uint2 pq; pq.x = pk2(vq.x, vq.y); pq.y = pk2(vq.z, vq.w);
        *(uint2*)(smem + swzb(LDS_KB, r, cB)) = pk;
        *(uint2*)(smem + swzb(LDS_GHT, r, cB)) = pq;
    }
    __syncthreads();   // -------- barrier 1: staging visible

    // ---- Qw B-fragments -> regs (same swizzled b128 pattern as before)
    short8 qf[2][4];
    #pragma unroll
    for (int kk = 0; kk < 2; ++kk) {
        uint32 cb = 64u * (uint32)kk + 16u * kq;
        #pragma unroll
        for (int tn = 0; tn < 4; ++tn)
            qf[kk][tn] = *(const short8*)(smem + swzb(LDS_GHT, 16u * (uint32)tn + r16, cb));
    }
    __syncthreads();   // -------- barrier 2: GHT free for reuse

    // ---- G = F^T F (64x64, K=128). Wave w: row band w x all col tiles.
    // A-fragment of band w == B-fragment of tile tn==w (8 tr16/chunk).
    f32x4 accG[4];
    #pragma unroll
    for (int i = 0; i < 4; ++i) accG[i] = (f32x4){0.f, 0.f, 0.f, 0.f};
    #pragma unroll
    for (int kk = 0; kk < 4; ++kk) {
        uint32 rA = (uint32)(32 * kk) + 8u * kq + trr;
        short4v b0l = tr16(ldsb + swzb(LDS_FB, rA,      0u  + trc));
        short4v b0h = tr16(ldsb + swzb(LDS_FB, rA + 4u, 0u  + trc));
        short4v b1l = tr16(ldsb + swzb(LDS_FB, rA,      32u + trc));
        short4v b1h = tr16(ldsb + swzb(LDS_FB, rA + 4u, 32u + trc));
        short4v b2l = tr16(ldsb + swzb(LDS_FB, rA,      64u + trc));
        short4v b2h = tr16(ldsb + swzb(LDS_FB, rA + 4u, 64u + trc));
        short4v b3l = tr16(ldsb + swzb(LDS_FB, rA,      96u + trc));
        short4v b3h = tr16(ldsb + swzb(LDS_FB, rA + 4u, 96u + trc));
        FENCE_LGKM0();
        short4v sal = wave == 0 ? b0l : wave == 1 ? b1l : wave == 2 ? b2l : b3l;
        short4v sah = wave == 0 ? b0h : wave == 1 ? b1h : wave == 2 ? b2h : b3h;
        short8 a = CAT8(sal, sah);
        accG[0] = MFMA(a, CAT8(b0l, b0h), accG[0]);
        accG[1] = MFMA(a, CAT8(b1l, b1h), accG[1]);
        accG[2] = MFMA(a, CAT8(b2l, b2h), accG[2]);
        accG[3] = MFMA(a, CAT8(b3l, b3h), accG[3]);
    }
    // write G band w (wave-local rows: only this wave reads them back)
    #pragma unroll
    for (int tn = 0; tn < 4; ++tn)
        #pragma unroll
        for (int r = 0; r < 4; ++r)
            *(ushort_t*)(smem + swzb(LDS_GHT, 16u * (uint32)wave + 4u * kq + (uint32)r,
                                     32u * (uint32)tn + 2u * r16)) = bfbits(accG[tn][r]);
    asm volatile("s_waitcnt lgkmcnt(0)" ::: "memory");  // wave-local RAW on GHT band
    __builtin_amdgcn_sched_barrier(0);

    // ---- HT = G @ Kw^T (64x64, K=64), band w in-place over G band w
    f32x4 accH[4];
    #pragma unroll
    for (int i = 0; i < 4; ++i) accH[i] = (f32x4){0.f, 0.f, 0.f, 0.f};
    #pragma unroll
    for (int kk = 0; kk < 2; ++kk) {
        uint32 cb = 64u * (uint32)kk + 16u * kq;
        short8 a = *(const short8*)(smem + swzb(LDS_GHT, 16u * (uint32)wave + r16, cb));
        #pragma unroll
        for (int tn = 0; tn < 4; ++tn) {
            short8 bb = *(const short8*)(smem + swzb(LDS_KB, 16u * (uint32)tn + r16, cb));
            accH[tn] = MFMA(a, bb, accH[tn]);
        }
    }
    asm volatile("" ::: "memory");  // keep HT stores below G reads
    #pragma unroll
    for (int tn = 0; tn < 4; ++tn)
        #pragma unroll
        for (int r = 0; r < 4; ++r)
            *(ushort_t*)(smem + swzb(LDS_GHT, 16u * (uint32)wave + 4u * kq + (uint32)r,
                                     32u * (uint32)tn + 2u * r16)) = bfbits(accH[tn][r]);
    __syncthreads();   // -------- barrier 3: HT visible to all waves

    // ---- T = F @ H (B from HT rows), QF = F @ Qw^T (B from qf regs). 128x64, K=64.
    f32x4 accT[2][4], accQ[2][4];
    #pragma unroll
    for (int i = 0; i < 2; ++i)
        #pragma unroll
        for (int j = 0; j < 4; ++j) {
            accT[i][j] = (f32x4){0.f, 0.f, 0.f, 0.f};
            accQ[i][j] = (f32x4){0.f, 0.f, 0.f, 0.f};
        }
    __builtin_amdgcn_s_setprio(1);
    #pragma unroll
    for (int kk = 0; kk < 2; ++kk) {
        uint32 cb = 64u * (uint32)kk + 16u * kq;
        short8 a0 = *(const short8*)(smem + swzb(LDS_FB, 16u * (uint32)(2 * wave + 0) + r16, cb));
        short8 a1 = *(const short8*)(smem + swzb(LDS_FB, 16u * (uint32)(2 * wave + 1) + r16, cb));
        #pragma unroll
        for (int tn = 0; tn < 4; ++tn) {
            short8 bt = *(const short8*)(smem + swzb(LDS_GHT, 16u * (uint32)tn + r16, cb));
            accT[0][tn] = MFMA(a0, bt, accT[0][tn]);
            accQ[0][tn] = MFMA(a0, qf[kk][tn], accQ[0][tn]);
            accT[1][tn] = MFMA(a1, bt, accT[1][tn]);
            accQ[1][tn] = MFMA(a1, qf[kk][tn], accQ[1][tn]);
        }
    }
    __builtin_amdgcn_s_setprio(0);

    // ---- epilogue: out = F .* T + QF
    float* og = out + (size_t)b * 8192;
    #pragma unroll
    for (int i2 = 0; i2 < 2; ++i2)
        #pragma unroll
        for (int tn = 0; tn < 4; ++tn)
            #pragma unroll
            for (int r = 0; r < 4; ++r) {
                uint32 n = 16u * (uint32)(2 * wave + i2) + 4u * kq + (uint32)r;
                uint32 d = 16u * (uint32)tn + r16;
                float f = bf2f(*(const ushort_t*)(smem + swzb(LDS_FB, n, 2u * d)));
                og[n * 64 + d] = fmaf(f, accT[i2][tn][r], accQ[i2][tn][r]);
            }
}

extern "C" void kernel_launch(void* const* d_in, const int* in_sizes, int n_in,
                              void* d_out, int out_size, void* d_ws, size_t ws_size,
                              hipStream_t stream) {
    const float* F  = (const float*)d_in[0];
    const float* Kw = (const float*)d_in[1];
    const float* Qw = (const float*)d_in[2];
    float* out = (float*)d_out;
    int Bt = in_sizes[0] / (128 * 64);   // 4096
    sam3e_kernel<<<dim3(Bt), dim3(256), 0, stream>>>(F, Kw, Qw, out);
}

// Round 10
// 46.016 us; speedup vs baseline: 1.8277x; 1.8277x over previous
//
#include <hip/hip_runtime.h>

typedef __attribute__((ext_vector_type(8))) short short8;
typedef __attribute__((ext_vector_type(4))) short short4v;
typedef __attribute__((ext_vector_type(4))) float f32x4;
typedef unsigned int uint32;
typedef unsigned short ushort_t;

// LDS layout (bytes). All bf16 tiles, 128B row stride, XOR-swizzled. 32 KB.
// GHT region is time-shared: Qw staging -> (barrier) -> G -> HT.
#define LDS_FB   0u        // F   [128][64]
#define LDS_GHT  16384u    // Qw staging, then G, then HT [64][64]
#define LDS_KB   24576u    // Kw  [64][64] row-major

__device__ __forceinline__ uint32 swzb(uint32 base, uint32 row, uint32 colByte) {
    return (base + row * 128u + colByte) ^ ((row & 7u) << 4);
}
__device__ __forceinline__ uint32 pk2(float lo, float hi) {   // v_cvt_pk_bf16_f32 (RNE)
    uint32 r;
    asm("v_cvt_pk_bf16_f32 %0, %1, %2" : "=v"(r) : "v"(lo), "v"(hi));
    return r;
}
__device__ __forceinline__ ushort_t bfbits(float x) {         // RNE f32 -> bf16 bits
    uint32 u = __float_as_uint(x);
    return (ushort_t)((u + 0x7FFFu + ((u >> 16) & 1u)) >> 16);
}
__device__ __forceinline__ float bf2f(ushort_t b) {
    return __uint_as_float(((uint32)b) << 16);
}
__device__ __forceinline__ short4v tr16(uint32 addr) {        // ds_read_b64_tr_b16
    short4v d;
    asm volatile("ds_read_b64_tr_b16 %0, %1" : "=v"(d) : "v"(addr));
    return d;
}
#define CAT8(lo, hi) __builtin_shufflevector(lo, hi, 0, 1, 2, 3, 4, 5, 6, 7)
#define MFMA(a, b, c) __builtin_amdgcn_mfma_f32_16x16x32_bf16((a), (b), (c), 0, 0, 0)
#define FENCE_LGKM0() do {                                                     \
    asm volatile("s_waitcnt lgkmcnt(0)" ::: "memory");                         \
    __builtin_amdgcn_sched_barrier(0);                                         \
} while (0)

__global__ __launch_bounds__(256, 4)
void sam3e_kernel(const float* __restrict__ F,
                  const float* __restrict__ Kw,
                  const float* __restrict__ Qw,
                  float* __restrict__ out) {
    __shared__ __align__(128) unsigned char smem[32768];
    const uint32 ldsb = (uint32)(size_t)(void*)smem;
    const int t    = threadIdx.x;
    const int lane = t & 63;
    const int wave = t >> 6;
    const int b    = blockIdx.x;
    const uint32 r16 = (uint32)(lane & 15);
    const uint32 kq  = (uint32)(lane >> 4);
    const uint32 trc = 8u * (r16 & 3u);
    const uint32 trr = r16 >> 2;

    // ---- stage F (batch b) -> bf16 LDS, row-major (HW cvt_pk)
    const float* Fg = F + (size_t)b * 8192;
    {
        int n0 = t >> 4;
        int c4 = (t & 15) * 4;
        #pragma unroll
        for (int i = 0; i < 8; ++i) {
            int n = n0 + 16 * i;
            float4 v = *(const float4*)(Fg + n * 64 + c4);
            uint2 pk; pk.x = pk2(v.x, v.y); pk.y = pk2(v.z, v.w);
            *(uint2*)(smem + swzb(LDS_FB, (uint32)n, (uint32)(2 * c4))) = pk;
        }
    }
    // ---- stage Kw -> KB, Qw -> GHT (time-shared; coalesced float4 loads)
    #pragma unroll
    for (int i = 0; i < 4; ++i) {
        int idx4 = t + 256 * i;
        uint32 r = (uint32)(idx4 >> 4);
        uint32 cB = (uint32)((idx4 & 15) * 8);
        float4 vk = *(const float4*)(Kw + 4 * idx4);
        float4 vq = *(const float4*)(Qw + 4 * idx4);
        uint2 pk; pk.x = pk2(vk.x, vk.y); pk.y = pk2(vk.z, vk.w);
        uint2 pq; pq.x = pk2(vq.x, vq.y); pq.y = pk2(vq.z, vq.w);
        *(uint2*)(smem + swzb(LDS_KB, r, cB)) = pk;
        *(uint2*)(smem + swzb(LDS_GHT, r, cB)) = pq;
    }
    __syncthreads();   // -------- barrier 1: staging visible

    // ---- Qw B-fragments -> regs (same swizzled b128 pattern as before)
    short8 qf[2][4];
    #pragma unroll
    for (int kk = 0; kk < 2; ++kk) {
        uint32 cb = 64u * (uint32)kk + 16u * kq;
        #pragma unroll
        for (int tn = 0; tn < 4; ++tn)
            qf[kk][tn] = *(const short8*)(smem + swzb(LDS_GHT, 16u * (uint32)tn + r16, cb));
    }
    __syncthreads();   // -------- barrier 2: GHT free for reuse

    // ---- G = F^T F (64x64, K=128). Wave w: row band w x all col tiles.
    // A-fragment of band w == B-fragment of tile tn==w (8 tr16/chunk).
    f32x4 accG[4];
    #pragma unroll
    for (int i = 0; i < 4; ++i) accG[i] = (f32x4){0.f, 0.f, 0.f, 0.f};
    #pragma unroll
    for (int kk = 0; kk < 4; ++kk) {
        uint32 rA = (uint32)(32 * kk) + 8u * kq + trr;
        short4v b0l = tr16(ldsb + swzb(LDS_FB, rA,      0u  + trc));
        short4v b0h = tr16(ldsb + swzb(LDS_FB, rA + 4u, 0u  + trc));
        short4v b1l = tr16(ldsb + swzb(LDS_FB, rA,      32u + trc));
        short4v b1h = tr16(ldsb + swzb(LDS_FB, rA + 4u, 32u + trc));
        short4v b2l = tr16(ldsb + swzb(LDS_FB, rA,      64u + trc));
        short4v b2h = tr16(ldsb + swzb(LDS_FB, rA + 4u, 64u + trc));
        short4v b3l = tr16(ldsb + swzb(LDS_FB, rA,      96u + trc));
        short4v b3h = tr16(ldsb + swzb(LDS_FB, rA + 4u, 96u + trc));
        FENCE_LGKM0();
        short4v sal = wave == 0 ? b0l : wave == 1 ? b1l : wave == 2 ? b2l : b3l;
        short4v sah = wave == 0 ? b0h : wave == 1 ? b1h : wave == 2 ? b2h : b3h;
        short8 a = CAT8(sal, sah);
        accG[0] = MFMA(a, CAT8(b0l, b0h), accG[0]);
        accG[1] = MFMA(a, CAT8(b1l, b1h), accG[1]);
        accG[2] = MFMA(a, CAT8(b2l, b2h), accG[2]);
        accG[3] = MFMA(a, CAT8(b3l, b3h), accG[3]);
    }
    // write G band w (wave-local rows: only this wave reads them back)
    #pragma unroll
    for (int tn = 0; tn < 4; ++tn)
        #pragma unroll
        for (int r = 0; r < 4; ++r)
            *(ushort_t*)(smem + swzb(LDS_GHT, 16u * (uint32)wave + 4u * kq + (uint32)r,
                                     32u * (uint32)tn + 2u * r16)) = bfbits(accG[tn][r]);
    asm volatile("s_waitcnt lgkmcnt(0)" ::: "memory");  // wave-local RAW on GHT band
    __builtin_amdgcn_sched_barrier(0);

    // ---- HT = G @ Kw^T (64x64, K=64), band w in-place over G band w
    f32x4 accH[4];
    #pragma unroll
    for (int i = 0; i < 4; ++i) accH[i] = (f32x4){0.f, 0.f, 0.f, 0.f};
    #pragma unroll
    for (int kk = 0; kk < 2; ++kk) {
        uint32 cb = 64u * (uint32)kk + 16u * kq;
        short8 a = *(const short8*)(smem + swzb(LDS_GHT, 16u * (uint32)wave + r16, cb));
        #pragma unroll
        for (int tn = 0; tn < 4; ++tn) {
            short8 bb = *(const short8*)(smem + swzb(LDS_KB, 16u * (uint32)tn + r16, cb));
            accH[tn] = MFMA(a, bb, accH[tn]);
        }
    }
    asm volatile("" ::: "memory");  // keep HT stores below G reads
    #pragma unroll
    for (int tn = 0; tn < 4; ++tn)
        #pragma unroll
        for (int r = 0; r < 4; ++r)
            *(ushort_t*)(smem + swzb(LDS_GHT, 16u * (uint32)wave + 4u * kq + (uint32)r,
                                     32u * (uint32)tn + 2u * r16)) = bfbits(accH[tn][r]);
    __syncthreads();   // -------- barrier 3: HT visible to all waves

    // ---- T = F @ H (B from HT rows), QF = F @ Qw^T (B from qf regs). 128x64, K=64.
    f32x4 accT[2][4], accQ[2][4];
    #pragma unroll
    for (int i = 0; i < 2; ++i)
        #pragma unroll
        for (int j = 0; j < 4; ++j) {
            accT[i][j] = (f32x4){0.f, 0.f, 0.f, 0.f};
            accQ[i][j] = (f32x4){0.f, 0.f, 0.f, 0.f};
        }
    __builtin_amdgcn_s_setprio(1);
    #pragma unroll
    for (int kk = 0; kk < 2; ++kk) {
        uint32 cb = 64u * (uint32)kk + 16u * kq;
        short8 a0 = *(const short8*)(smem + swzb(LDS_FB, 16u * (uint32)(2 * wave + 0) + r16, cb));
        short8 a1 = *(const short8*)(smem + swzb(LDS_FB, 16u * (uint32)(2 * wave + 1) + r16, cb));
        #pragma unroll
        for (int tn = 0; tn < 4; ++tn) {
            short8 bt = *(const short8*)(smem + swzb(LDS_GHT, 16u * (uint32)tn + r16, cb));
            accT[0][tn] = MFMA(a0, bt, accT[0][tn]);
            accQ[0][tn] = MFMA(a0, qf[kk][tn], accQ[0][tn]);
            accT[1][tn] = MFMA(a1, bt, accT[1][tn]);
            accQ[1][tn] = MFMA(a1, qf[kk][tn], accQ[1][tn]);
        }
    }
    __builtin_amdgcn_s_setprio(0);

    // ---- epilogue: out = F .* T + QF
    float* og = out + (size_t)b * 8192;
    #pragma unroll
    for (int i2 = 0; i2 < 2; ++i2)
        #pragma unroll
        for (int tn = 0; tn < 4; ++tn)
            #pragma unroll
            for (int r = 0; r < 4; ++r) {
                uint32 n = 16u * (uint32)(2 * wave + i2) + 4u * kq + (uint32)r;
                uint32 d = 16u * (uint32)tn + r16;
                float f = bf2f(*(const ushort_t*)(smem + swzb(LDS_FB, n, 2u * d)));
                og[n * 64 + d] = fmaf(f, accT[i2][tn][r], accQ[i2][tn][r]);
            }
}

extern "C" void kernel_launch(void* const* d_in, const int* in_sizes, int n_in,
                              void* d_out, int out_size, void* d_ws, size_t ws_size,
                              hipStream_t stream) {
    const float* F  = (const float*)d_in[0];
    const float* Kw = (const float*)d_in[1];
    const float* Qw = (const float*)d_in[2];
    float* out = (float*)d_out;
    int Bt = in_sizes[0] / (128 * 64);   // 4096
    sam3e_kernel<<<dim3(Bt), dim3(256), 0, stream>>>(F, Kw, Qw, out);
}